// Round 6
// baseline (686.167 us; speedup 1.0000x reference)
//
#include <hip/hip_runtime.h>
#include <math.h>

#define KM 16
#define KS 64
#define TWO_PI_F 6.283185307179586477f

// (256,2): allow up to 256 VGPR/wave. All private arrays (h2[64], th[48]) are
// indexed ONLY by compile-time constants (full unroll) so SROA promotes them —
// rounds 4/5 spilled ~950 MB/launch because `h2[i]` sat under `#pragma unroll 2`.
__global__ __launch_bounds__(256, 2)
void mobius_spline_kernel(const float* __restrict__ r_in,
                          const float* __restrict__ z_in,
                          const float* __restrict__ theta_w,
                          const float* __restrict__ theta_h,
                          const float* __restrict__ theta_d,
                          const float* __restrict__ W1,
                          const float* __restrict__ b1,
                          const float* __restrict__ W2,
                          const float* __restrict__ b2,
                          const float* __restrict__ W3,
                          const float* __restrict__ b3,
                          float* __restrict__ out,
                          int n)
{
    __shared__ float sxk[KS + 1], syk[KS + 1], sdk[KS + 1];
    __shared__ float stmp[2 * KS];

    const int tid = threadIdx.x;

    if (tid < 64) {  // exactly wave 0: spline tables
        float vw = theta_w[tid];
        float vh = theta_h[tid];
        float mw = vw, mh = vh;
        #pragma unroll
        for (int off = 32; off > 0; off >>= 1) {
            mw = fmaxf(mw, __shfl_xor(mw, off));
            mh = fmaxf(mh, __shfl_xor(mh, off));
        }
        const float ew = expf(vw - mw);
        const float eh = expf(vh - mh);
        float sumw = ew, sumh = eh;
        #pragma unroll
        for (int off = 32; off > 0; off >>= 1) {
            sumw += __shfl_xor(sumw, off);
            sumh += __shfl_xor(sumh, off);
        }
        stmp[tid]      = ew / sumw * 2.0f;   // width
        stmp[KS + tid] = eh / sumh * 2.0f;   // height

        if (tid < KS - 1) {
            const float x = theta_d[tid];
            const float sp = (x > 20.0f) ? x : log1pf(expf(x));
            sdk[1 + tid] = sp + 0.001f;
        }
        if (tid == 0) { sdk[0] = 1.0f; sdk[KS] = 1.0f; }
    }
    __syncthreads();
    if (tid == 0) {  // sequential cumsum matches jnp.cumsum accumulation order
        float cx = -1.0f, cy = -1.0f;
        sxk[0] = -1.0f; syk[0] = -1.0f;
        #pragma unroll 1
        for (int i = 0; i < KS; i++) {
            cx += stmp[i];
            cy += stmp[KS + i];
            sxk[i + 1] = cx;
            syk[i + 1] = cy;
        }
    }
    __syncthreads();

    const int idx = blockIdx.x * 256 + tid;
    if (idx >= n) return;

    const float rv = r_in[idx];
    const float zz = z_in[idx];

    // ---------------- spline ----------------
    int lo = 0, hi = KS + 1;
    while (lo < hi) {
        const int mid = (lo + hi) >> 1;
        if (sxk[mid] < rv) lo = mid + 1; else hi = mid;
    }
    int k = lo;
    k = (k == 0) ? 1 : k;
    k = (k == KS + 1) ? KS : k;
    k -= 1;
    const float x_k = sxk[k], x_nk = sxk[k + 1];
    const float y_k = syk[k], y_nk = syk[k + 1];
    const float d_k = sdk[k], d_nk = sdk[k + 1];
    const float dxk = x_nk - x_k;
    const float s_k = (y_nk - y_k) / dxk;
    const float eps = (rv - x_k) / dxk;
    const float ome = 1.0f - eps;
    const float den = s_k + (d_nk + d_k - 2.0f * s_k) * eps * ome;
    const float tr  = y_k + (y_nk - y_k) * (s_k * eps * eps + d_k * eps * ome) / den;
    const float dtr = s_k * s_k * (d_nk * eps * eps + 2.0f * s_k * eps * ome + d_k * ome * ome)
                      / (den * den);

    // ---------------- MLP phase 1: h2 = relu(relu(rv*W1+b1) @ W2 + b2) ------
    float h2[64];
    #pragma unroll
    for (int i = 0; i < 64; i++) h2[i] = b2[i];          // uniform -> s_load

    #pragma unroll 2
    for (int j = 0; j < 64; j++) {
        const float h1j = fmaxf(fmaf(rv, W1[j], b1[j]), 0.0f);  // uniform s_loads
        const float* __restrict__ w2row = &W2[j * 64];
        #pragma unroll
        for (int i = 0; i < 64; i++)                       // full unroll: h2 idx constant
            h2[i] = fmaf(h1j, w2row[i], h2[i]);            // v_fmac v,s,v
    }
    #pragma unroll
    for (int i = 0; i < 64; i++) h2[i] = fmaxf(h2[i], 0.0f);

    // ---------------- MLP phase 2: theta[48] = h2 @ W3 + b3 ------------------
    // FULLY unrolled: every th[] index is a literal -> SROA keeps th in VGPRs.
    float th[48];
    #pragma unroll
    for (int q = 0; q < 48; q++) th[q] = b3[q];
    #pragma unroll
    for (int i = 0; i < 64; i++) {
        const float hv = h2[i];
        const float* __restrict__ w3r = &W3[i * 48];
        #pragma unroll
        for (int q = 0; q < 48; q++) th[q] = fmaf(hv, w3r[q], th[q]);
    }

    // ---------------- mobius (fully unrolled, static th indices) -------------
    float mx = th[0];
    #pragma unroll
    for (int q = 1; q < 16; q++) mx = fmaxf(mx, th[q]);

    float cz, sz2;
    sincosf(zz, &sz2, &cz);
    float wsum = 0.0f, tsum = 0.0f, dsum = 0.0f;

    #pragma unroll
    for (int q = 0; q < 16; q++) {
        const float rwx = th[16 + 2 * q];
        const float rwy = th[17 + 2 * q];
        const float nrm = sqrtf(rwx * rwx + rwy * rwy);
        const float scl = 0.99f / (1.0f + nrm);
        const float wx = scl * rwx, wy = scl * rwy;
        const float wn2 = wx * wx + wy * wy;
        const float omw = 1.0f - wn2;
        // h_map(zv, w)
        const float dzx = cz - wx, dzy = sz2 - wy;
        const float dn2z = dzx * dzx + dzy * dzy;
        const float cf = omw / dn2z;
        const float hzx = cf * dzx - wx;
        const float hzy = cf * dzy - wy;
        // h_map((1,0), w)
        const float d0x = 1.0f - wx, d0y = -wy;
        const float dn20 = d0x * d0x + d0y * d0y;
        const float c0 = omw / dn20;
        const float h0x = c0 * d0x - wx;
        const float h0y = c0 * d0y - wy;
        // tx = (atan2(hz) - atan2(h0)) mod 2pi == atan2(cross, dot) mod 2pi
        const float cross = hzy * h0x - hzx * h0y;
        const float dotp  = hzx * h0x + hzy * h0y;
        float tx = atan2f(cross, dotp);
        tx = (tx >= 0.0f) ? tx : tx + TWO_PI_F;
        const float ew = expf(th[q] - mx);
        wsum += ew;
        tsum += ew * tx;
        // |dh| = cf exactly: dh = cf*(dz - 2u(u.dz)) is a reflection of unit dz
        dsum += ew * cf;
    }

    const float inv = 1.0f / wsum;
    const float tz  = tsum * inv;
    const float dtz = dsum * inv;
    const float ldj = logf(dtr) + logf(dtz);

    out[idx]         = tr;
    out[n + idx]     = tz;
    out[2 * n + idx] = ldj;
}

extern "C" void kernel_launch(void* const* d_in, const int* in_sizes, int n_in,
                              void* d_out, int out_size, void* d_ws, size_t ws_size,
                              hipStream_t stream) {
    const int n = in_sizes[0];  // 1,000,000
    const int blocks = (n + 255) / 256;
    hipLaunchKernelGGL(mobius_spline_kernel, dim3(blocks), dim3(256), 0, stream,
                       (const float*)d_in[0], (const float*)d_in[1],
                       (const float*)d_in[2], (const float*)d_in[3],
                       (const float*)d_in[4], (const float*)d_in[5],
                       (const float*)d_in[6], (const float*)d_in[7],
                       (const float*)d_in[8], (const float*)d_in[9],
                       (const float*)d_in[10],
                       (float*)d_out, n);
}

// Round 7
// 358.682 us; speedup vs baseline: 1.9130x; 1.9130x over previous
//
#include <hip/hip_runtime.h>
#include <math.h>

#define KM 16
#define KS 64
#define TWO_PI_F 6.283185307179586477f

// Pre-pass: W2T[i][j] = W2[j][i] into workspace, so the fused main loop can
// stream W2 columns as contiguous scalar-load rows.
__global__ void transpose_w2_kernel(const float* __restrict__ W2, float* __restrict__ W2T) {
    const int i = blockIdx.x * 256 + threadIdx.x;   // 4096 elements
    if (i < 64 * 64) {
        const int r = i >> 6, c = i & 63;
        W2T[c * 64 + r] = W2[r * 64 + c];
    }
}

// No private array is EVER dynamically indexed:
//  - h1/h2 never exist as arrays (fused, remat/scalar temps)
//  - th[48]: written by 48-wide static inner loop, read by macro-expanded
//    literal indices -> SROA-promotable independent of unroller heuristics.
// (Rounds 4-6 lost 200-950 MB/launch to scratch because some h2/th access
//  kept a runtime index whenever the unroller balked.)
__global__ __launch_bounds__(256, 2)
void mobius_spline_kernel(const float* __restrict__ r_in,
                          const float* __restrict__ z_in,
                          const float* __restrict__ theta_w,
                          const float* __restrict__ theta_h,
                          const float* __restrict__ theta_d,
                          const float* __restrict__ W1,
                          const float* __restrict__ b1,
                          const float* __restrict__ W2T,
                          const float* __restrict__ b2,
                          const float* __restrict__ W3,
                          const float* __restrict__ b3,
                          float* __restrict__ out,
                          int n)
{
    __shared__ float sxk[KS + 1], syk[KS + 1], sdk[KS + 1];
    __shared__ float stmp[2 * KS];

    const int tid = threadIdx.x;

    if (tid < 64) {  // exactly wave 0: spline tables
        float vw = theta_w[tid];
        float vh = theta_h[tid];
        float mw = vw, mh = vh;
        #pragma unroll
        for (int off = 32; off > 0; off >>= 1) {
            mw = fmaxf(mw, __shfl_xor(mw, off));
            mh = fmaxf(mh, __shfl_xor(mh, off));
        }
        const float ew = expf(vw - mw);
        const float eh = expf(vh - mh);
        float sumw = ew, sumh = eh;
        #pragma unroll
        for (int off = 32; off > 0; off >>= 1) {
            sumw += __shfl_xor(sumw, off);
            sumh += __shfl_xor(sumh, off);
        }
        stmp[tid]      = ew / sumw * 2.0f;   // width
        stmp[KS + tid] = eh / sumh * 2.0f;   // height

        if (tid < KS - 1) {
            const float x = theta_d[tid];
            const float sp = (x > 20.0f) ? x : log1pf(expf(x));
            sdk[1 + tid] = sp + 0.001f;
        }
        if (tid == 0) { sdk[0] = 1.0f; sdk[KS] = 1.0f; }
    }
    __syncthreads();
    if (tid == 0) {  // sequential cumsum matches jnp.cumsum accumulation order
        float cx = -1.0f, cy = -1.0f;
        sxk[0] = -1.0f; syk[0] = -1.0f;
        #pragma unroll 1
        for (int i = 0; i < KS; i++) {
            cx += stmp[i];
            cy += stmp[KS + i];
            sxk[i + 1] = cx;
            syk[i + 1] = cy;
        }
    }
    __syncthreads();

    const int idx = blockIdx.x * 256 + tid;
    if (idx >= n) return;

    const float rv = r_in[idx];
    const float zz = z_in[idx];

    // ---------------- spline ----------------
    int lo = 0, hi = KS + 1;
    while (lo < hi) {
        const int mid = (lo + hi) >> 1;
        if (sxk[mid] < rv) lo = mid + 1; else hi = mid;
    }
    int k = lo;
    k = (k == 0) ? 1 : k;
    k = (k == KS + 1) ? KS : k;
    k -= 1;
    const float x_k = sxk[k], x_nk = sxk[k + 1];
    const float y_k = syk[k], y_nk = syk[k + 1];
    const float d_k = sdk[k], d_nk = sdk[k + 1];
    const float dxk = x_nk - x_k;
    const float s_k = (y_nk - y_k) / dxk;
    const float eps = (rv - x_k) / dxk;
    const float ome = 1.0f - eps;
    const float den = s_k + (d_nk + d_k - 2.0f * s_k) * eps * ome;
    const float tr  = y_k + (y_nk - y_k) * (s_k * eps * eps + d_k * eps * ome) / den;
    const float dtr = s_k * s_k * (d_nk * eps * eps + 2.0f * s_k * eps * ome + d_k * ome * ome)
                      / (den * den);

    // ------- fused MLP: theta = relu(relu(h1) @ W2 + b2) @ W3 + b3 ----------
    float th[48];
    #pragma unroll
    for (int q = 0; q < 48; q++) th[q] = b3[q];

    #pragma unroll 1
    for (int i = 0; i < 64; i++) {
        // h2_i = relu( b2_i + sum_j h1_j * W2[j][i] ); h1_j remats from rv
        float a0 = b2[i], a1 = 0.0f, a2 = 0.0f, a3 = 0.0f;
        const float* __restrict__ w2c = &W2T[i * 64];
        #pragma unroll
        for (int j4 = 0; j4 < 16; j4++) {
            const float h1a = fmaxf(fmaf(rv, W1[4 * j4 + 0], b1[4 * j4 + 0]), 0.0f);
            const float h1b = fmaxf(fmaf(rv, W1[4 * j4 + 1], b1[4 * j4 + 1]), 0.0f);
            const float h1c = fmaxf(fmaf(rv, W1[4 * j4 + 2], b1[4 * j4 + 2]), 0.0f);
            const float h1d = fmaxf(fmaf(rv, W1[4 * j4 + 3], b1[4 * j4 + 3]), 0.0f);
            a0 = fmaf(h1a, w2c[4 * j4 + 0], a0);
            a1 = fmaf(h1b, w2c[4 * j4 + 1], a1);
            a2 = fmaf(h1c, w2c[4 * j4 + 2], a2);
            a3 = fmaf(h1d, w2c[4 * j4 + 3], a3);
        }
        const float hv = fmaxf((a0 + a1) + (a2 + a3), 0.0f);
        const float* __restrict__ w3r = &W3[i * 48];
        #pragma unroll
        for (int q = 0; q < 48; q++) th[q] = fmaf(hv, w3r[q], th[q]);
    }

    // ---------------- mobius: macro-expanded, literal th indices -------------
    float mx = th[0];
    #pragma unroll
    for (int q = 1; q < 16; q++) mx = fmaxf(mx, th[q]);

    float cz, sz2;
    sincosf(zz, &sz2, &cz);
    float wsum = 0.0f, tsum = 0.0f, dsum = 0.0f;

#define MOB(q) { \
    const float rwx = th[16 + 2 * (q)]; \
    const float rwy = th[17 + 2 * (q)]; \
    const float nrm = sqrtf(rwx * rwx + rwy * rwy); \
    const float scl = 0.99f / (1.0f + nrm); \
    const float wx = scl * rwx, wy = scl * rwy; \
    const float wn2 = wx * wx + wy * wy; \
    const float omw = 1.0f - wn2; \
    const float dzx = cz - wx, dzy = sz2 - wy; \
    const float dn2z = dzx * dzx + dzy * dzy; \
    const float cf = omw / dn2z; \
    const float hzx = cf * dzx - wx; \
    const float hzy = cf * dzy - wy; \
    const float d0x = 1.0f - wx, d0y = -wy; \
    const float dn20 = d0x * d0x + d0y * d0y; \
    const float c0 = omw / dn20; \
    const float h0x = c0 * d0x - wx; \
    const float h0y = c0 * d0y - wy; \
    const float cross = hzy * h0x - hzx * h0y; \
    const float dotp  = hzx * h0x + hzy * h0y; \
    float tx = atan2f(cross, dotp); \
    tx = (tx >= 0.0f) ? tx : tx + TWO_PI_F; \
    const float ew = expf(th[(q)] - mx); \
    wsum += ew; \
    tsum += ew * tx; \
    dsum += ew * cf; \
}
    MOB(0)  MOB(1)  MOB(2)  MOB(3)
    MOB(4)  MOB(5)  MOB(6)  MOB(7)
    MOB(8)  MOB(9)  MOB(10) MOB(11)
    MOB(12) MOB(13) MOB(14) MOB(15)
#undef MOB

    const float inv = 1.0f / wsum;
    const float tz  = tsum * inv;
    const float dtz = dsum * inv;
    const float ldj = logf(dtr) + logf(dtz);

    out[idx]         = tr;
    out[n + idx]     = tz;
    out[2 * n + idx] = ldj;
}

extern "C" void kernel_launch(void* const* d_in, const int* in_sizes, int n_in,
                              void* d_out, int out_size, void* d_ws, size_t ws_size,
                              hipStream_t stream) {
    const int n = in_sizes[0];  // 1,000,000
    float* W2T = (float*)d_ws;  // 16 KB of workspace

    hipLaunchKernelGGL(transpose_w2_kernel, dim3(16), dim3(256), 0, stream,
                       (const float*)d_in[7], W2T);

    const int blocks = (n + 255) / 256;
    hipLaunchKernelGGL(mobius_spline_kernel, dim3(blocks), dim3(256), 0, stream,
                       (const float*)d_in[0], (const float*)d_in[1],
                       (const float*)d_in[2], (const float*)d_in[3],
                       (const float*)d_in[4], (const float*)d_in[5],
                       (const float*)d_in[6], W2T,
                       (const float*)d_in[8], (const float*)d_in[9],
                       (const float*)d_in[10],
                       (float*)d_out, n);
}